// Round 11
// baseline (267.616 us; speedup 1.0000x reference)
//
#include <hip/hip_runtime.h>

namespace {
constexpr int B = 1024, Q = 128, P = 32, N = 128, D = 64, K = 160;

// ---------------- mean distance over cdist(x, y_pos) ----------------
__global__ __launch_bounds__(256) void k_meandist(
    const float* __restrict__ x, const float* __restrict__ y_pos,
    double* __restrict__ ws) {
  __shared__ float Yp[P][D];
  __shared__ float ysq[P];
  __shared__ float red[4];
  const int b = blockIdx.x, tid = threadIdx.x;
  const float* yb = y_pos + (size_t)b * P * D;
  for (int i = tid; i < P * D / 4; i += 256)
    reinterpret_cast<float4*>(&Yp[0][0])[i] = reinterpret_cast<const float4*>(yb)[i];
  __syncthreads();
  if (tid < P) {
    float s = 0.f;
    for (int d = 0; d < D; ++d) { float v = Yp[tid][d]; s = fmaf(v, v, s); }
    ysq[tid] = s;
  }
  __syncthreads();
  const int q = tid >> 1, ph = tid & 1;
  const float* xq = x + ((size_t)b * Q + q) * D;
  float acc[16];
#pragma unroll
  for (int j = 0; j < 16; ++j) acc[j] = 0.f;
  float xsq = 0.f;
#pragma unroll 1
  for (int d4 = 0; d4 < 16; ++d4) {
    float4 xv = reinterpret_cast<const float4*>(xq)[d4];
    xsq = fmaf(xv.x, xv.x, fmaf(xv.y, xv.y, fmaf(xv.z, xv.z, fmaf(xv.w, xv.w, xsq))));
#pragma unroll
    for (int j = 0; j < 16; ++j) {
      float4 yv = reinterpret_cast<const float4*>(&Yp[ph * 16 + j][0])[d4];
      acc[j] = fmaf(xv.x, yv.x, fmaf(xv.y, yv.y, fmaf(xv.z, yv.z, fmaf(xv.w, yv.w, acc[j]))));
    }
  }
  float dsum = 0.f;
#pragma unroll
  for (int j = 0; j < 16; ++j) {
    float d2 = xsq + ysq[ph * 16 + j] - 2.f * acc[j];
    dsum += sqrtf(fmaxf(d2, 0.f));
  }
#pragma unroll
  for (int m = 1; m < 64; m <<= 1) dsum += __shfl_xor(dsum, m);
  if ((tid & 63) == 0) red[tid >> 6] = dsum;
  __syncthreads();
  if (tid == 0)
    atomicAdd(ws, (double)(red[0] + red[1] + red[2] + red[3]));
}

// ---------------- fused drift kernel: 1024 threads, one block/batch --------
// R10 lesson: 512-thr blocks never got 2-block co-residency (22.7% occ).
// A 1024-thr block = 16 waves = 4 waves/EU GUARANTEED (block atomicity),
// while waves_per_eu min=2 keeps the 128-VGPR budget. Per-thread tiles
// halved (zz[4][5]=20) -> peak live ~60 regs, 2x headroom -> no spill.
// Full C lives in LDS (132.6 KB <= 160 KB/CU): no global C round-trip.
__global__
__attribute__((amdgpu_flat_work_group_size(1024, 1024)))
__attribute__((amdgpu_waves_per_eu(2, 4)))
void k_drift3(
    const float* __restrict__ x, const float* __restrict__ y_pos,
    const float* __restrict__ y_neg, double* __restrict__ ws) {
  // LDS map (floats), total 33160 f = 132640 B:
  //  [0,10240)      Y4 [160][16] f4 row-rotated by k (reused as merge buf)
  //  [10240,31360)  C [160][132] f32; X4c [128][8] f4 aliases the front
  //  [31360,31744)  rss [3][128]
  //  [31744,32224)  css [3][160] -> rsqrt in place
  //  [32224,32608)  uss [3][128] -> /rs in place  (sum over pos k)
  //  [32608,32992)  vss [3][128] -> /rs in place  (sum over neg k)
  //  [32992,33152)  ysq [160]
  //  [33152,33160)  redd (4 doubles)
  __shared__ __align__(16) float SM[33160];
  float4* Y4  = (float4*)SM;
  float4* X4c = (float4*)(SM + 10240);
  float*  Cs  = SM + 10240;
  float4* C4  = (float4*)(SM + 10240);
  float* rss = SM + 31360;
  float* css = SM + 31744;
  float* uss = SM + 32224;
  float* vss = SM + 32608;
  float* ysq = SM + 32992;
  double* redd = (double*)(SM + 33152);

  const int b = blockIdx.x, tid = threadIdx.x;
  const float4* yn4 = (const float4*)(y_neg + (size_t)b * N * D);
  const float4* yp4 = (const float4*)(y_pos + (size_t)b * P * D);
  const float4* xg  = (const float4*)(x + (size_t)b * Q * D);

  // ---- stage Y (rotated) + zero sums ----
  for (int idx = tid; idx < K * 16; idx += 1024) {
    int k = idx >> 4, d4 = idx & 15;
    float4 v = (k < N) ? yn4[k * 16 + d4] : yp4[(k - N) * 16 + d4];
    Y4[k * 16 + ((d4 + k) & 15)] = v;
  }
  if (tid < 384) { rss[tid] = 0.f; uss[tid] = 0.f; vss[tid] = 0.f; }
  __syncthreads();
  if (tid < K) {
    float s = 0.f;
#pragma unroll
    for (int c = 0; c < 16; ++c) {
      float4 v = Y4[tid * 16 + ((c + tid) & 15)];
      s = fmaf(v.x, v.x, fmaf(v.y, v.y, fmaf(v.z, v.z, fmaf(v.w, v.w, s))));
    }
    ysq[tid] = s;
  }

  // producer mapping: qg = tid&31 -> q in [4qg, 4qg+4); kt = tid>>5 -> k = kt+32j
  const int qg = tid & 31, kt = tid >> 5;
  const int qb = qg * 4;

  float zz[4][5], xs4[4];
#pragma unroll
  for (int i = 0; i < 4; ++i) {
    xs4[i] = 0.f;
#pragma unroll
    for (int j = 0; j < 5; ++j) zz[i][j] = 0.f;
  }

  // ---- dist phase: X staged in 2 chunks of 8 f4-cols ----
#pragma unroll 1
  for (int ch = 0; ch < 2; ++ch) {
    if (ch) __syncthreads();          // previous chunk fully consumed
    {
      int q = tid >> 3, c = tid & 7;  // one f4 store per thread
      X4c[q * 8 + ((c + (q >> 2)) & 7)] = xg[q * 16 + ch * 8 + c];
    }
    __syncthreads();
#pragma unroll 2
    for (int d4 = 0; d4 < 8; ++d4) {
      const int gd4 = ch * 8 + d4;
      const int rx = (d4 + qg) & 7;   // (q>>2)==qg for all 4 owned rows
      float4 xv[4];
#pragma unroll
      for (int i = 0; i < 4; ++i) xv[i] = X4c[(qb + i) * 8 + rx];
#pragma unroll
      for (int i = 0; i < 4; ++i)
        xs4[i] = fmaf(xv[i].x, xv[i].x, fmaf(xv[i].y, xv[i].y,
                 fmaf(xv[i].z, xv[i].z, fmaf(xv[i].w, xv[i].w, xs4[i]))));
#pragma unroll
      for (int j = 0; j < 5; ++j) {
        const int k_ = kt + 32 * j;
        float4 yv = Y4[k_ * 16 + ((gd4 + k_) & 15)];
#pragma unroll
        for (int i = 0; i < 4; ++i)
          zz[i][j] = fmaf(xv[i].x, yv.x, fmaf(xv[i].y, yv.y,
                     fmaf(xv[i].z, yv.z, fmaf(xv[i].w, yv.w, zz[i][j]))));
      }
    }
  }

  const float meand = (float)(ws[0] * (1.0 / ((double)B * Q * P)));
  const float invt2 = 1.0f / fmaxf(meand, 1e-6f);
#pragma unroll
  for (int i = 0; i < 4; ++i)
#pragma unroll
    for (int j = 0; j < 5; ++j) {
      const int k_ = kt + 32 * j;
      float d2 = xs4[i] + ysq[k_] - 2.f * zz[i][j];
      zz[i][j] = __expf(-sqrtf(fmaxf(d2, 0.f)) * invt2);
    }

  // ---- pass 1: row sums (rss, atomic across 16 waves) / col sums (css) ----
  // wave layout: lane<32 -> kt=2w, lane>=32 -> kt=2w+1; qg = lane&31.
#pragma unroll
  for (int t = 0; t < 3; ++t) {
    float ers[4] = {0.f, 0.f, 0.f, 0.f};
    float ecs[5] = {0.f, 0.f, 0.f, 0.f, 0.f};
#pragma unroll
    for (int i = 0; i < 4; ++i)
#pragma unroll
      for (int j = 0; j < 5; ++j) {
        float z = zz[i][j], f;
        if (t == 2) f = z;
        else if (t == 1) f = z * z;
        else { float z2 = z * z, z4 = z2 * z2; f = z4 * z4 * z2; }
        ers[i] += f; ecs[j] += f;
      }
#pragma unroll
    for (int j = 0; j < 5; ++j) {    // col sum over 32 qg (within half-wave)
      float v = ecs[j];
      v += __shfl_xor(v, 1); v += __shfl_xor(v, 2);
      v += __shfl_xor(v, 4); v += __shfl_xor(v, 8); v += __shfl_xor(v, 16);
      if (qg == 0) css[t * 160 + kt + 32 * j] = v;   // unique (kt,j) writer
    }
#pragma unroll
    for (int i = 0; i < 4; ++i) {    // row: pair kt halves, atomic across waves
      float v = ers[i];
      v += __shfl_xor(v, 32);
      if ((tid & 63) < 32) atomicAdd(&rss[t * 128 + qb + i], v);
    }
  }
  __syncthreads();
  if (tid < 480) css[tid] = rsqrtf(css[tid]);
  __syncthreads();

  // ---- pass 2: sum_pos (uss) / sum_neg (vss) of e*ics per (temp, q) ----
#pragma unroll
  for (int t = 0; t < 3; ++t) {
    float icr[5];
#pragma unroll
    for (int j = 0; j < 5; ++j) icr[j] = css[t * 160 + kt + 32 * j];
    float uu[4] = {0.f, 0.f, 0.f, 0.f};
    float vv[4] = {0.f, 0.f, 0.f, 0.f};
#pragma unroll
    for (int i = 0; i < 4; ++i)
#pragma unroll
      for (int j = 0; j < 5; ++j) {
        float z = zz[i][j], f;
        if (t == 2) f = z;
        else if (t == 1) f = z * z;
        else { float z2 = z * z, z4 = z2 * z2; f = z4 * z4 * z2; }
        float a = f * icr[j];
        if (j == 4) uu[i] += a; else vv[i] += a;   // j==4 <=> k>=128 <=> pos
      }
#pragma unroll
    for (int i = 0; i < 4; ++i) {
      float u = uu[i]; u += __shfl_xor(u, 32);
      float v = vv[i]; v += __shfl_xor(v, 32);
      if ((tid & 63) < 32) {
        atomicAdd(&uss[t * 128 + qb + i], u);
        atomicAdd(&vss[t * 128 + qb + i], v);
      }
    }
  }
  __syncthreads();
  if (tid < 384) {
    float inv = 1.0f / rss[tid];
    uss[tid] *= inv;
    vss[tid] *= inv;
  }
  __syncthreads();

  // ---- coefficient production into C (f32, row stride 132) ----
  {
    float ic0a[5], ic1a[5], ic2a[5];
#pragma unroll
    for (int j = 0; j < 5; ++j) {
      const int k_ = kt + 32 * j;
      ic0a[j] = css[k_]; ic1a[j] = css[160 + k_]; ic2a[j] = css[320 + k_];
    }
#pragma unroll
    for (int i = 0; i < 4; ++i) {
      const int q2 = qb + i;
      float u0 = uss[q2], u1 = uss[128 + q2], u2 = uss[256 + q2];
      float v0 = vss[q2], v1 = vss[128 + q2], v2 = vss[256 + q2];
#pragma unroll
      for (int j = 0; j < 5; ++j) {
        const int k_ = kt + 32 * j;
        const bool pos = (j == 4);
        float a0 = pos ? v0 : u0, a1 = pos ? v1 : u1, a2 = pos ? v2 : u2;
        float z = zz[i][j], z2 = z * z, z4 = z2 * z2, z10 = z4 * z4 * z2;
        float c = fmaf(z, ic2a[j] * a2, fmaf(z2, ic1a[j] * a1, z10 * (ic0a[j] * a0)));
        Cs[k_ * 132 + q2] = pos ? c : -c;
      }
    }
  }
  __syncthreads();

  // ---- drift GEMM: 4-way k-split; kc owns 40 k, covers all (q,d) ----
  const int kc = tid >> 8, qc = (tid >> 3) & 31, dc = tid & 7;
  float dr[4][8];
#pragma unroll
  for (int i = 0; i < 4; ++i)
#pragma unroll
    for (int n = 0; n < 8; ++n) dr[i][n] = 0.f;

#pragma unroll 4
  for (int kk = 0; kk < 40; ++kk) {
    const int k_ = kc * 40 + kk;
    float4 ca = C4[k_ * 33 + qc];
    float4 y0 = Y4[k_ * 16 + ((2 * dc + k_) & 15)];
    float4 y1 = Y4[k_ * 16 + ((2 * dc + 1 + k_) & 15)];
#define GACC(ii, cv)                               \
    dr[ii][0] = fmaf(cv, y0.x, dr[ii][0]);         \
    dr[ii][1] = fmaf(cv, y0.y, dr[ii][1]);         \
    dr[ii][2] = fmaf(cv, y0.z, dr[ii][2]);         \
    dr[ii][3] = fmaf(cv, y0.w, dr[ii][3]);         \
    dr[ii][4] = fmaf(cv, y1.x, dr[ii][4]);         \
    dr[ii][5] = fmaf(cv, y1.y, dr[ii][5]);         \
    dr[ii][6] = fmaf(cv, y1.z, dr[ii][6]);         \
    dr[ii][7] = fmaf(cv, y1.w, dr[ii][7]);
    GACC(0, ca.x) GACC(1, ca.y) GACC(2, ca.z) GACC(3, ca.w)
#undef GACC
  }
  __syncthreads();   // GEMM done -> Y region reusable as merge buffer

  // ---- merge 4 kc partials (via freed Y region) + loss reduction ----
  float4* FB = Y4;
  const int c0 = (2 * dc + qc) & 15, c1 = (2 * dc + 1 + qc) & 15;
  if (kc > 0) {
    const int off = (kc - 1) * 2048;
#pragma unroll
    for (int i = 0; i < 4; ++i) {
      const int q = qc * 4 + i;
      FB[off + q * 16 + c0] = make_float4(dr[i][0], dr[i][1], dr[i][2], dr[i][3]);
      FB[off + q * 16 + c1] = make_float4(dr[i][4], dr[i][5], dr[i][6], dr[i][7]);
    }
  }
  __syncthreads();
  if (kc == 0) {
    float tot = 0.f;
#pragma unroll
    for (int i = 0; i < 4; ++i) {
      const int q = qc * 4 + i;
      float4 s0 = FB[q * 16 + c0];
      float4 t0 = FB[2048 + q * 16 + c0];
      float4 u0 = FB[4096 + q * 16 + c0];
      float a0 = dr[i][0] + s0.x + t0.x + u0.x;
      float a1 = dr[i][1] + s0.y + t0.y + u0.y;
      float a2 = dr[i][2] + s0.z + t0.z + u0.z;
      float a3 = dr[i][3] + s0.w + t0.w + u0.w;
      tot = fmaf(a0, a0, tot); tot = fmaf(a1, a1, tot);
      tot = fmaf(a2, a2, tot); tot = fmaf(a3, a3, tot);
      float4 s1 = FB[q * 16 + c1];
      float4 t1 = FB[2048 + q * 16 + c1];
      float4 u1 = FB[4096 + q * 16 + c1];
      float a4 = dr[i][4] + s1.x + t1.x + u1.x;
      float a5 = dr[i][5] + s1.y + t1.y + u1.y;
      float a6 = dr[i][6] + s1.z + t1.z + u1.z;
      float a7 = dr[i][7] + s1.w + t1.w + u1.w;
      tot = fmaf(a4, a4, tot); tot = fmaf(a5, a5, tot);
      tot = fmaf(a6, a6, tot); tot = fmaf(a7, a7, tot);
    }
#pragma unroll
    for (int m = 1; m < 64; m <<= 1) tot += __shfl_xor(tot, m);
    if ((tid & 63) == 0) redd[tid >> 6] = (double)tot;   // waves 0..3
  }
  __syncthreads();
  if (tid == 0)
    atomicAdd(ws + 1, redd[0] + redd[1] + redd[2] + redd[3]);
}

__global__ void k_final(const double* __restrict__ ws, float* __restrict__ out) {
  out[0] = (float)(ws[1] / ((double)B * Q * D));
}

}  // namespace

extern "C" void kernel_launch(void* const* d_in, const int* in_sizes, int n_in,
                              void* d_out, int out_size, void* d_ws, size_t ws_size,
                              hipStream_t stream) {
  const float* x = (const float*)d_in[0];
  const float* y_pos = (const float*)d_in[1];
  const float* y_neg = (const float*)d_in[2];
  float* out = (float*)d_out;
  double* ws = (double*)d_ws;

  hipMemsetAsync(d_ws, 0, 2 * sizeof(double), stream);
  k_meandist<<<B, 256, 0, stream>>>(x, y_pos, ws);
  k_drift3<<<B, 1024, 0, stream>>>(x, y_pos, y_neg, ws);
  k_final<<<1, 1, 0, stream>>>(ws, out);
}